// Round 1
// baseline (218.076 us; speedup 1.0000x reference)
//
#include <hip/hip_runtime.h>

// Problem: B=256, T=256 trees, E=64, H=4.
// out[b,t,e] = sum_{j!=t, h} relu(x[b,j,:]·W1[t,j,:,h] + b1[t,j,h]) * W2[t, pos(j)*H+h, e] + b2[t,e]
// pos(j) = j if j<t else j-1.

namespace {

constexpr int T_ = 256;
constexpr int E_ = 64;
constexpr int H_ = 4;
constexpr int K2_ = (T_ - 1) * H_;   // 1020
constexpr int I_ = 4;                // trees per block
constexpr int JC = 8;                // j's per chunk (K=32 for GEMM2)
constexpr int NCHUNK = T_ / JC;      // 32

typedef float  f32x4  __attribute__((ext_vector_type(4)));
typedef short  bf16x8 __attribute__((ext_vector_type(8)));

__device__ inline unsigned short f2b(float f) {
    union { float f; unsigned u; } v; v.f = f;
    unsigned r = v.u + 0x7fffu + ((v.u >> 16) & 1u);   // RNE bf16
    return (unsigned short)(r >> 16);
}

__device__ inline bf16x8 pack8(f32x4 a, f32x4 b) {
    bf16x8 r;
    r[0] = (short)f2b(a[0]); r[1] = (short)f2b(a[1]);
    r[2] = (short)f2b(a[2]); r[3] = (short)f2b(a[3]);
    r[4] = (short)f2b(b[0]); r[5] = (short)f2b(b[1]);
    r[6] = (short)f2b(b[2]); r[7] = (short)f2b(b[3]);
    return r;
}

} // namespace

// Block: 256 threads = 4 waves. blockIdx.x in [0,256):
//   i0 = (bid>>2)*4 (4 trees), b0 = (bid&3)*64 (64 batches).
// Wave w: GEMM1 M-tile w (16 batches), GEMM2 tree i0+w.
__global__ __launch_bounds__(256, 1) void fused_forest_kernel(
    const float* __restrict__ x,   // [256][256][64]   (B,T,E), x[:,0] squeezed
    const float* __restrict__ W1,  // [256][256][64][4]
    const float* __restrict__ b1,  // [256][256][4]
    const float* __restrict__ W2,  // [256][1020][64]
    const float* __restrict__ b2,  // [256][64]
    float* __restrict__ out)       // [256][256][64]
{
    // LDS (all bf16 except b1c). Rows padded to 72/40 elems (144B/80B, 16B-aligned,
    // 2-way max bank aliasing on b128 reads = free).
    __shared__ __align__(16) unsigned short W1t[JC][16][72];  // [jj][(i*4+h)][e]
    __shared__ __align__(16) unsigned short Pbuf[I_][64][40]; // [i][b_loc][kk=jj*4+h]
    __shared__ __align__(16) unsigned short W2b[I_][E_][40];  // [i][e][kk]
    __shared__ float b1c[JC][16];                             // [jj][(i*4+h)]

    const int bid = blockIdx.x;
    const int i0  = (bid >> 2) << 2;   // tree base
    const int b0  = (bid & 3) << 6;    // batch base
    const int tid = threadIdx.x;
    const int w   = tid >> 6;          // wave 0..3
    const int l   = tid & 63;
    const int r16 = l & 15;            // fragment row/col index
    const int kg  = l >> 4;            // k-group 0..3

    f32x4 acc[4][4];                   // [mt][nt] -> wave's 64x64 f32 tile for tree i0+w
    #pragma unroll
    for (int mt = 0; mt < 4; ++mt)
        #pragma unroll
        for (int nt = 0; nt < 4; ++nt)
            acc[mt][nt] = (f32x4){0.f, 0.f, 0.f, 0.f};

    for (int c = 0; c < NCHUNK; ++c) {
        const int j0 = c * JC;
        __syncthreads();   // previous chunk's GEMM2 readers done before restaging

        // ---- stage b1 chunk: b1c[jj][i*4+h] ----
        if (tid < 128) {
            const int jj = tid >> 4, ih = tid & 15;
            b1c[jj][ih] = b1[((i0 + (ih >> 2)) * T_ + (j0 + jj)) * H_ + (ih & 3)];
        }

        // ---- stage W1t[jj][(i*4+h)][e] = bf16(W1[i0+i][j0+jj][e][h]) ----
        {
            const int i  = tid >> 6;          // 0..3
            const int jj = (tid >> 3) & 7;    // 0..7
            const int g  = tid & 7;           // 32 consecutive f32 each
            const float* src = W1 + (((size_t)(i0 + i) * T_ + (j0 + jj)) * E_) * H_ + g * 32;
            #pragma unroll
            for (int s = 0; s < 32; s += 4) {
                f32x4 v = *(const f32x4*)(src + s);
                #pragma unroll
                for (int q = 0; q < 4; ++q) {
                    const int ff = g * 32 + s + q;       // ff = e*4 + h
                    W1t[jj][(i << 2) | (ff & 3)][ff >> 2] = f2b(v[q]);
                }
            }
        }

        // ---- stage W2b[i][e][kk] = bf16(W2[t][pos(j)*4+h][e]), 0 if j==t ----
        {
            const int i    = tid >> 6;
            const int kk   = (tid & 63) >> 1;      // 0..31
            const int e0   = (tid & 1) * 32;
            const int tabs = i0 + i;
            const int j    = j0 + (kk >> 2);
            const int hh   = kk & 3;
            if (j == tabs) {
                #pragma unroll
                for (int s = 0; s < 32; ++s) W2b[i][e0 + s][kk] = 0;
            } else {
                const int ksrc = ((j < tabs) ? j : j - 1) * 4 + hh;
                const float* src = W2 + ((size_t)tabs * K2_ + ksrc) * E_ + e0;
                #pragma unroll
                for (int s = 0; s < 32; s += 4) {
                    f32x4 v = *(const f32x4*)(src + s);
                    #pragma unroll
                    for (int q = 0; q < 4; ++q)
                        W2b[i][e0 + s + q][kk] = f2b(v[q]);
                }
            }
        }
        __syncthreads();

        // ---- GEMM1: P[b,(i,h)] = relu(x_j · W1t + b1), N=16 = (i,h) ----
        {
            const int brow = b0 + (w << 4) + r16;     // A-frag row (m = lane&15)
            #pragma unroll
            for (int jj = 0; jj < JC; ++jj) {
                const float* xrow = x + ((size_t)brow * T_ + (j0 + jj)) * E_ + (kg << 3);
                f32x4 xa = *(const f32x4*)(xrow);
                f32x4 xb = *(const f32x4*)(xrow + 4);
                f32x4 xc = *(const f32x4*)(xrow + 32);
                f32x4 xd = *(const f32x4*)(xrow + 36);
                bf16x8 a0 = pack8(xa, xb);            // k = kg*8..+8
                bf16x8 a1 = pack8(xc, xd);            // k = 32+kg*8..+8
                bf16x8 w0 = *(const bf16x8*)&W1t[jj][r16][(kg << 3)];
                bf16x8 w1 = *(const bf16x8*)&W1t[jj][r16][32 + (kg << 3)];
                f32x4 cf = (f32x4){0.f, 0.f, 0.f, 0.f};
                cf = __builtin_amdgcn_mfma_f32_16x16x32_bf16(a0, w0, cf, 0, 0, 0);
                cf = __builtin_amdgcn_mfma_f32_16x16x32_bf16(a1, w1, cf, 0, 0, 0);
                // C layout: col = lane&15 = (i*4+h), row = kg*4 + r (batch-local)
                const float bias = b1c[jj][r16];
                #pragma unroll
                for (int r = 0; r < 4; ++r) {
                    float vv = cf[r] + bias;
                    vv = vv > 0.f ? vv : 0.f;
                    Pbuf[r16 >> 2][(w << 4) + (kg << 2) + r][(jj << 2) | (r16 & 3)] = f2b(vv);
                }
            }
        }
        __syncthreads();

        // ---- GEMM2: acc += P_i · W2b_i  (M=64, N=64, K=32) ----
        {
            bf16x8 a2[4], bb[4];
            #pragma unroll
            for (int mt = 0; mt < 4; ++mt)
                a2[mt] = *(const bf16x8*)&Pbuf[w][(mt << 4) + r16][(kg << 3)];
            #pragma unroll
            for (int nt = 0; nt < 4; ++nt)
                bb[nt] = *(const bf16x8*)&W2b[w][(nt << 4) + r16][(kg << 3)];
            #pragma unroll
            for (int mt = 0; mt < 4; ++mt)
                #pragma unroll
                for (int nt = 0; nt < 4; ++nt)
                    acc[mt][nt] = __builtin_amdgcn_mfma_f32_16x16x32_bf16(
                        a2[mt], bb[nt], acc[mt][nt], 0, 0, 0);
        }
    }

    // ---- epilogue: out[b, i0+w, e] = acc + b2 ----
    const int tabs = i0 + w;
    #pragma unroll
    for (int mt = 0; mt < 4; ++mt) {
        const int b = b0 + (mt << 4) + (kg << 2);
        #pragma unroll
        for (int nt = 0; nt < 4; ++nt) {
            const int e = (nt << 4) + r16;
            const float bias2 = b2[tabs * E_ + e];
            #pragma unroll
            for (int r = 0; r < 4; ++r)
                out[((size_t)(b + r) * T_ + tabs) * E_ + e] = acc[mt][nt][r] + bias2;
        }
    }
}

extern "C" void kernel_launch(void* const* d_in, const int* in_sizes, int n_in,
                              void* d_out, int out_size, void* d_ws, size_t ws_size,
                              hipStream_t stream) {
    const float* x  = (const float*)d_in[0];
    const float* W1 = (const float*)d_in[1];
    const float* b1 = (const float*)d_in[2];
    const float* W2 = (const float*)d_in[3];
    const float* b2 = (const float*)d_in[4];
    float* out = (float*)d_out;
    (void)in_sizes; (void)n_in; (void)out_size; (void)d_ws; (void)ws_size;

    hipLaunchKernelGGL(fused_forest_kernel, dim3(256), dim3(256), 0, stream,
                       x, W1, b1, W2, b2, out);
}

// Round 2
// 145.843 us; speedup vs baseline: 1.4953x; 1.4953x over previous
//
#include <hip/hip_runtime.h>

// Problem: B=256, T=256 trees, E=64, H=4.
// out[b,t,e] = sum_{j!=t, h} relu(x[b,j,:]·W1[t,j,:,h] + b1[t,j,h]) * W2[t, pos(j)*H+h, e] + b2[t,e]
// pos(j) = j if j<t else j-1.
//
// R2: grid 1024 = 64 tree-groups x 4 batch-groups x 4 j-groups; atomic accumulate.
// LDS 33.3 KB -> 4 blocks/CU -> ~45% occupancy. x pre-cast to bf16 in d_ws.

namespace {

constexpr int T_ = 256;
constexpr int E_ = 64;
constexpr int K2_ = 1020;            // (T-1)*H
constexpr int JC = 4;                // j's per chunk (K=16 for GEMM2, zero-padded to 32)
constexpr int CHUNKS = 16;           // 64 j's per block / JC

typedef float  f32x4  __attribute__((ext_vector_type(4)));
typedef short  bf16x8 __attribute__((ext_vector_type(8)));

__device__ inline unsigned short f2b(float f) {
    union { float f; unsigned u; } v; v.f = f;
    unsigned r = v.u + 0x7fffu + ((v.u >> 16) & 1u);   // RNE bf16
    return (unsigned short)(r >> 16);
}

__device__ inline bf16x8 pack8(f32x4 a, f32x4 b) {
    bf16x8 r;
    r[0] = (short)f2b(a[0]); r[1] = (short)f2b(a[1]);
    r[2] = (short)f2b(a[2]); r[3] = (short)f2b(a[3]);
    r[4] = (short)f2b(b[0]); r[5] = (short)f2b(b[1]);
    r[6] = (short)f2b(b[2]); r[7] = (short)f2b(b[3]);
    return r;
}

} // namespace

// out[b,t,e] = b2[t,e]  (accumulation base for the atomic partial sums)
__global__ __launch_bounds__(256) void init_out_kernel(
    const float* __restrict__ b2, float* __restrict__ out)
{
    const int idx = blockIdx.x * 256 + threadIdx.x;    // 1,048,576 f32x4's
    ((f32x4*)out)[idx] = ((const f32x4*)b2)[idx & 4095];
}

// x (f32, 4.19M elems) -> bf16 in workspace
__global__ __launch_bounds__(256) void xcast_kernel(
    const float* __restrict__ x, unsigned short* __restrict__ xb)
{
    const int idx = blockIdx.x * 256 + threadIdx.x;    // 524,288 groups of 8
    f32x4 a = ((const f32x4*)x)[2 * idx];
    f32x4 b = ((const f32x4*)x)[2 * idx + 1];
    ((bf16x8*)xb)[idx] = pack8(a, b);
}

// Block: 256 threads = 4 waves. bid: tg = bid>>4 (4 trees), bg = (bid>>2)&3
// (64 batches), jg = bid&3 (64 j's). Wave w: GEMM1 M-tile w, GEMM2 tree i0+w.
template <bool XBF>
__global__ __launch_bounds__(256, 4) void fused_forest_kernel(
    const void*  __restrict__ xv,  // bf16 [256][256][64] (XBF) or f32 (fallback)
    const float* __restrict__ W1,  // [256][256][64][4]
    const float* __restrict__ b1,  // [256][256][4]
    const float* __restrict__ W2,  // [256][1020][64]
    float* __restrict__ out)       // [256][256][64], pre-initialized to b2
{
    __shared__ __align__(16) unsigned short W1t[JC][16][72];  // [jj][(i*4+h)][e]  9216 B
    __shared__ __align__(16) unsigned short Pbuf[4][64][24];  // [i][b_loc][kk]   12288 B
    __shared__ __align__(16) unsigned short W2b[4][64][24];   // [i][e][kk]       12288 B
    __shared__ float b1c[JC][16];                             //                    256 B

    const int bid = blockIdx.x;
    const int i0  = (bid >> 4) << 2;        // tree base
    const int b0  = ((bid >> 2) & 3) << 6;  // batch base
    const int j0g = (bid & 3) << 6;         // j-range base (64 j's)
    const int tid = threadIdx.x;
    const int w   = tid >> 6;               // wave 0..3
    const int l   = tid & 63;
    const int r16 = l & 15;
    const int kg  = l >> 4;                 // k-group 0..3

    f32x4 acc[4][4];
    #pragma unroll
    for (int mt = 0; mt < 4; ++mt)
        #pragma unroll
        for (int nt = 0; nt < 4; ++nt)
            acc[mt][nt] = (f32x4){0.f, 0.f, 0.f, 0.f};

    for (int c = 0; c < CHUNKS; ++c) {
        const int j0 = j0g + c * JC;
        __syncthreads();   // prev chunk's readers done before restaging

        // ---- stage b1c[jj][i*4+h] ----
        if (tid < 64) {
            const int jj = tid >> 4, ih = tid & 15;
            b1c[jj][ih] = b1[((i0 + (ih >> 2)) * T_ + (j0 + jj)) * 4 + (ih & 3)];
        }

        // ---- stage W1t[jj][(i*4+h)][e] = bf16(W1[i0+i][j0+jj][e][h]) ----
        {
            const int i  = tid >> 6;          // 0..3
            const int jj = (tid >> 4) & 3;    // 0..3
            const int g  = tid & 15;          // 16 consecutive f32 each
            const float* src = W1 + (((size_t)(i0 + i) * T_ + (j0 + jj)) * E_) * 4 + g * 16;
            #pragma unroll
            for (int s = 0; s < 16; s += 4) {
                f32x4 v = *(const f32x4*)(src + s);
                #pragma unroll
                for (int q = 0; q < 4; ++q) {
                    const int ff = g * 16 + s + q;       // ff = e*4 + h
                    W1t[jj][(i << 2) | (ff & 3)][ff >> 2] = f2b(v[q]);
                }
            }
        }

        // ---- stage W2b[i][e][kk] = bf16(W2[t][pos(j)*4+h][e]), 0 if j==t ----
        {
            const int i    = tid >> 6;
            const int kk   = (tid & 63) >> 2;      // 0..15
            const int e0   = (tid & 3) * 16;
            const int tabs = i0 + i;
            const int j    = j0 + (kk >> 2);
            const int hh   = kk & 3;
            if (j == tabs) {
                #pragma unroll
                for (int s = 0; s < 16; ++s) W2b[i][e0 + s][kk] = 0;
            } else {
                const int ksrc = ((j < tabs) ? j : j - 1) * 4 + hh;
                const float* src = W2 + ((size_t)tabs * K2_ + ksrc) * E_ + e0;
                #pragma unroll
                for (int s = 0; s < 16; s += 4) {
                    f32x4 v = *(const f32x4*)(src + s);
                    #pragma unroll
                    for (int q = 0; q < 4; ++q)
                        W2b[i][e0 + s + q][kk] = f2b(v[q]);
                }
            }
        }
        __syncthreads();

        // ---- GEMM1: P[b,(i,h)] = relu(x_j · W1t + b1), M=16/wave, N=16, K=64 ----
        {
            const int brow = b0 + (w << 4) + r16;
            #pragma unroll
            for (int jj = 0; jj < JC; ++jj) {
                bf16x8 a0, a1;
                if (XBF) {
                    const unsigned short* xr =
                        (const unsigned short*)xv + ((size_t)brow * T_ + (j0 + jj)) * E_;
                    a0 = *(const bf16x8*)(xr + (kg << 3));
                    a1 = *(const bf16x8*)(xr + 32 + (kg << 3));
                } else {
                    const float* xr = (const float*)xv + ((size_t)brow * T_ + (j0 + jj)) * E_ + (kg << 3);
                    a0 = pack8(*(const f32x4*)xr, *(const f32x4*)(xr + 4));
                    a1 = pack8(*(const f32x4*)(xr + 32), *(const f32x4*)(xr + 36));
                }
                bf16x8 w0 = *(const bf16x8*)&W1t[jj][r16][(kg << 3)];
                bf16x8 w1 = *(const bf16x8*)&W1t[jj][r16][32 + (kg << 3)];
                f32x4 cf = (f32x4){0.f, 0.f, 0.f, 0.f};
                cf = __builtin_amdgcn_mfma_f32_16x16x32_bf16(a0, w0, cf, 0, 0, 0);
                cf = __builtin_amdgcn_mfma_f32_16x16x32_bf16(a1, w1, cf, 0, 0, 0);
                const float bias = b1c[jj][r16];
                #pragma unroll
                for (int r = 0; r < 4; ++r) {
                    float vv = cf[r] + bias;
                    vv = vv > 0.f ? vv : 0.f;
                    Pbuf[r16 >> 2][(w << 4) + (kg << 2) + r][(jj << 2) | (r16 & 3)] = f2b(vv);
                }
            }
        }
        __syncthreads();

        // ---- GEMM2: acc += P_i · W2b_i  (M=64, N=64, K=16 zero-padded to 32) ----
        {
            bf16x8 a2[4], bb[4];
            const bf16x8 z = (bf16x8){0,0,0,0,0,0,0,0};
            #pragma unroll
            for (int mt = 0; mt < 4; ++mt)
                a2[mt] = (kg < 2) ? *(const bf16x8*)&Pbuf[w][(mt << 4) + r16][(kg << 3)] : z;
            #pragma unroll
            for (int nt = 0; nt < 4; ++nt)
                bb[nt] = (kg < 2) ? *(const bf16x8*)&W2b[w][(nt << 4) + r16][(kg << 3)] : z;
            #pragma unroll
            for (int mt = 0; mt < 4; ++mt)
                #pragma unroll
                for (int nt = 0; nt < 4; ++nt)
                    acc[mt][nt] = __builtin_amdgcn_mfma_f32_16x16x32_bf16(
                        a2[mt], bb[nt], acc[mt][nt], 0, 0, 0);
        }
    }

    // ---- epilogue: out[b, i0+w, e] += acc (out pre-set to b2) ----
    const int tabs = i0 + w;
    #pragma unroll
    for (int mt = 0; mt < 4; ++mt) {
        const int b = b0 + (mt << 4) + (kg << 2);
        #pragma unroll
        for (int nt = 0; nt < 4; ++nt) {
            const int e = (nt << 4) + r16;
            #pragma unroll
            for (int r = 0; r < 4; ++r)
                unsafeAtomicAdd(&out[((size_t)(b + r) * T_ + tabs) * E_ + e],
                                acc[mt][nt][r]);
        }
    }
}

extern "C" void kernel_launch(void* const* d_in, const int* in_sizes, int n_in,
                              void* d_out, int out_size, void* d_ws, size_t ws_size,
                              hipStream_t stream) {
    const float* x  = (const float*)d_in[0];
    const float* W1 = (const float*)d_in[1];
    const float* b1 = (const float*)d_in[2];
    const float* W2 = (const float*)d_in[3];
    const float* b2 = (const float*)d_in[4];
    float* out = (float*)d_out;
    (void)in_sizes; (void)n_in; (void)out_size;

    const size_t xbf_bytes = (size_t)256 * 256 * 64 * 2;   // 8.4 MB
    const bool xbf = ws_size >= xbf_bytes && d_ws != nullptr;

    hipLaunchKernelGGL(init_out_kernel, dim3(4096), dim3(256), 0, stream, b2, out);

    if (xbf) {
        hipLaunchKernelGGL(xcast_kernel, dim3(2048), dim3(256), 0, stream,
                           x, (unsigned short*)d_ws);
        hipLaunchKernelGGL(fused_forest_kernel<true>, dim3(1024), dim3(256), 0, stream,
                           (const void*)d_ws, W1, b1, W2, out);
    } else {
        hipLaunchKernelGGL(fused_forest_kernel<false>, dim3(1024), dim3(256), 0, stream,
                           (const void*)x, W1, b1, W2, out);
    }
}